// Round 7
// baseline (439.650 us; speedup 1.0000x reference)
//
#include <hip/hip_runtime.h>
#include <hip/hip_bf16.h>

// LIF neuron update (SpikeLayer.update_neurons), one step.
// Elementwise over N = 64*256*32*32 fp32 elements.
// Outputs (concatenated in d_out): psp, mem_out, refrac_out, spiketrain_out.
//
// Constants: DT=1.0, TAU_REFRAC=2.0, V_THRESH=1.0, LEAK=true, TIME=5.0
//
// The `spiketrain` input is dead (never read by the math) -> not loaded.
// Traffic: 3 reads + 4 writes x 67.1 MB = 470 MB -> ~75 us floor @ 6.3 TB/s.
//
// R4/R5 evidence: headline dur_us (~424) = 2x 1-GiB harness re-poison fills
// (~162 us each, 6.6 TB/s = chip's demonstrated write ceiling) + kernel
// (~95-100 us => ~4.8 TB/s). This round: non-temporal stores for the 4
// output streams (write-once, never re-read) -> no L2/L3 write allocation,
// cache stays available for the input streams.
// R6 fix: __builtin_nontemporal_store needs a native clang vector type,
// not HIP's float4 class -> use ext_vector_type(4).

#define LIF_TIME        5.0f
#define LIF_TAU_REFRAC  2.0f
#define LIF_V_THRESH    1.0f
#define LIF_LEAK_DEC    0.1f   /* 0.1 * dt, dt = 1.0 */

typedef float vfloat4 __attribute__((ext_vector_type(4)));

__global__ __launch_bounds__(256) void lif_update_kernel(
    const float4* __restrict__ impulse,
    const float4* __restrict__ mem,
    const float4* __restrict__ refrac_until,
    vfloat4* __restrict__ psp_out,
    vfloat4* __restrict__ mem_out,
    vfloat4* __restrict__ refrac_out,
    vfloat4* __restrict__ spiketrain_out,
    int n4)
{
    const int i = blockIdx.x * blockDim.x + threadIdx.x;
    if (i >= n4) return;

    const float4 imp = impulse[i];
    const float4 m   = mem[i];
    const float4 ru  = refrac_until[i];

    vfloat4 psp, mo, ro, so;

    #pragma unroll
    for (int j = 0; j < 4; ++j) {
        const float impj = (&imp.x)[j];
        const float mj   = (&m.x)[j];
        const float ruj  = (&ru.x)[j];

        // masked impulse: zero while refractory
        float nm = mj + ((ruj > LIF_TIME) ? 0.0f : impj);
        // leak on positive membrane
        nm = (nm > 0.0f) ? (nm - LIF_LEAK_DEC) : nm;

        const bool spiked = (nm >= LIF_V_THRESH);

        psp[j] = spiked ? LIF_V_THRESH : 0.0f;
        mo[j]  = spiked ? 0.0f : nm;
        ro[j]  = spiked ? (LIF_TIME + LIF_TAU_REFRAC) : ruj;
        so[j]  = spiked ? LIF_TIME : 0.0f;
    }

    // Non-temporal: outputs are write-once, never re-read -> bypass cache
    // allocation so L2/L3 stays available for the input streams.
    __builtin_nontemporal_store(psp, &psp_out[i]);
    __builtin_nontemporal_store(mo,  &mem_out[i]);
    __builtin_nontemporal_store(ro,  &refrac_out[i]);
    __builtin_nontemporal_store(so,  &spiketrain_out[i]);
}

extern "C" void kernel_launch(void* const* d_in, const int* in_sizes, int n_in,
                              void* d_out, int out_size, void* d_ws, size_t ws_size,
                              hipStream_t stream) {
    (void)n_in; (void)d_ws; (void)ws_size;

    const float* impulse      = (const float*)d_in[0];
    const float* mem          = (const float*)d_in[1];
    const float* refrac_until = (const float*)d_in[2];
    // d_in[3] (spiketrain) is dead -> not read.

    const int n = in_sizes[0];          // 16,777,216
    float* out = (float*)d_out;         // 4*n elements, concatenated

    float* psp_out        = out;
    float* mem_out        = out + (size_t)n;
    float* refrac_out     = out + 2 * (size_t)n;
    float* spiketrain_out = out + 3 * (size_t)n;

    const int n4 = n / 4;               // 4,194,304 (divisible)

    const int block = 256;
    const int grid = (n4 + block - 1) / block;   // 16384 blocks, exact

    lif_update_kernel<<<grid, block, 0, stream>>>(
        (const float4*)impulse, (const float4*)mem, (const float4*)refrac_until,
        (vfloat4*)psp_out, (vfloat4*)mem_out, (vfloat4*)refrac_out,
        (vfloat4*)spiketrain_out, n4);
}

// Round 9
// 425.491 us; speedup vs baseline: 1.0333x; 1.0333x over previous
//
#include <hip/hip_runtime.h>
#include <hip/hip_bf16.h>

// LIF neuron update (SpikeLayer.update_neurons), one step.
// Elementwise over N = 64*256*32*32 fp32 elements.
// Outputs (concatenated in d_out): psp, mem_out, refrac_out, spiketrain_out.
//
// Constants: DT=1.0, TAU_REFRAC=2.0, V_THRESH=1.0, LEAK=true, TIME=5.0
//
// The `spiketrain` input is dead (never read by the math) -> not loaded.
// Traffic: 3 reads + 4 writes x 67.1 MB = 470 MB -> ~75 us floor @ 6.3 TB/s.
//
// Evidence so far:
//  R4/R5: headline (~424) = 2x 1-GiB harness poison fills (~162 us each,
//         6.6 TB/s write ceiling) + kernel (~100 us => ~4.8 TB/s).
//  R7:    NT *stores* regressed (+14 us): poison fill leaves d_out dirty in
//         L2/L3; NT stores bypass the merge -> poison lines written back to
//         HBM on top of the NT data. Normal stores merge in-cache. REVERTED.
//  R8:    NT *loads* instead: inputs are read-once and clean; normal loads
//         would allocate and evict the dirty poison lines of d_out before
//         our stores overwrite them (wasted 0xAA writeback). NT loads keep
//         the read stream out of the cache so stores hit & merge the poison
//         lines. Stores stay normal.

#define LIF_TIME        5.0f
#define LIF_TAU_REFRAC  2.0f
#define LIF_V_THRESH    1.0f
#define LIF_LEAK_DEC    0.1f   /* 0.1 * dt, dt = 1.0 */

typedef float vfloat4 __attribute__((ext_vector_type(4)));

__global__ __launch_bounds__(256) void lif_update_kernel(
    const vfloat4* __restrict__ impulse,
    const vfloat4* __restrict__ mem,
    const vfloat4* __restrict__ refrac_until,
    vfloat4* __restrict__ psp_out,
    vfloat4* __restrict__ mem_out,
    vfloat4* __restrict__ refrac_out,
    vfloat4* __restrict__ spiketrain_out,
    int n4)
{
    const int i = blockIdx.x * blockDim.x + threadIdx.x;
    if (i >= n4) return;

    // Non-temporal loads: read-once streams, no reuse; avoid evicting the
    // dirty (poisoned) d_out lines that our stores are about to overwrite.
    const vfloat4 imp = __builtin_nontemporal_load(&impulse[i]);
    const vfloat4 m   = __builtin_nontemporal_load(&mem[i]);
    const vfloat4 ru  = __builtin_nontemporal_load(&refrac_until[i]);

    vfloat4 psp, mo, ro, so;

    #pragma unroll
    for (int j = 0; j < 4; ++j) {
        const float impj = imp[j];
        const float mj   = m[j];
        const float ruj  = ru[j];

        // masked impulse: zero while refractory
        float nm = mj + ((ruj > LIF_TIME) ? 0.0f : impj);
        // leak on positive membrane
        nm = (nm > 0.0f) ? (nm - LIF_LEAK_DEC) : nm;

        const bool spiked = (nm >= LIF_V_THRESH);

        psp[j] = spiked ? LIF_V_THRESH : 0.0f;
        mo[j]  = spiked ? 0.0f : nm;
        ro[j]  = spiked ? (LIF_TIME + LIF_TAU_REFRAC) : ruj;
        so[j]  = spiked ? LIF_TIME : 0.0f;
    }

    // Normal stores: merge with the resident dirty poison lines in-cache.
    psp_out[i]        = psp;
    mem_out[i]        = mo;
    refrac_out[i]     = ro;
    spiketrain_out[i] = so;
}

extern "C" void kernel_launch(void* const* d_in, const int* in_sizes, int n_in,
                              void* d_out, int out_size, void* d_ws, size_t ws_size,
                              hipStream_t stream) {
    (void)n_in; (void)d_ws; (void)ws_size;

    const float* impulse      = (const float*)d_in[0];
    const float* mem          = (const float*)d_in[1];
    const float* refrac_until = (const float*)d_in[2];
    // d_in[3] (spiketrain) is dead -> not read.

    const int n = in_sizes[0];          // 16,777,216
    float* out = (float*)d_out;         // 4*n elements, concatenated

    float* psp_out        = out;
    float* mem_out        = out + (size_t)n;
    float* refrac_out     = out + 2 * (size_t)n;
    float* spiketrain_out = out + 3 * (size_t)n;

    const int n4 = n / 4;               // 4,194,304 (divisible)

    const int block = 256;
    const int grid = (n4 + block - 1) / block;   // 16384 blocks, exact

    lif_update_kernel<<<grid, block, 0, stream>>>(
        (const vfloat4*)impulse, (const vfloat4*)mem, (const vfloat4*)refrac_until,
        (vfloat4*)psp_out, (vfloat4*)mem_out, (vfloat4*)refrac_out,
        (vfloat4*)spiketrain_out, n4);
}